// Round 1
// baseline (916.768 us; speedup 1.0000x reference)
//
#include <hip/hip_runtime.h>
#include <stdint.h>

#define N_FEATS 131072
#define IN_SZ   256
#define HID     1024
#define OUT_SZ  256
#define NE      16

typedef __attribute__((ext_vector_type(8))) short short8;
typedef __attribute__((ext_vector_type(4))) float floatx4;

__device__ inline unsigned short f32_bf16(float f) {
    unsigned int u = __builtin_bit_cast(unsigned int, f);
    u += 0x7FFFu + ((u >> 16) & 1u);   // round-to-nearest-even
    return (unsigned short)(u >> 16);
}

// ---------------- bucketing ----------------
__global__ void k_hist(const int* __restrict__ ids, int* __restrict__ counts) {
    __shared__ int lc[NE];
    int t = threadIdx.x;
    if (t < NE) lc[t] = 0;
    __syncthreads();
    for (int i = blockIdx.x * blockDim.x + t; i < N_FEATS; i += gridDim.x * blockDim.x)
        atomicAdd(&lc[ids[i]], 1);
    __syncthreads();
    if (t < NE) atomicAdd(&counts[t], lc[t]);
}

__global__ void k_scan(const int* __restrict__ counts, int* __restrict__ offsets,
                       int* __restrict__ tilep) {
    if (threadIdx.x == 0 && blockIdx.x == 0) {
        int o = 0, tp = 0;
        for (int e = 0; e < NE; e++) {
            offsets[e] = o; tilep[e] = tp;
            o += counts[e];
            tp += (counts[e] + 63) >> 6;
        }
        offsets[NE] = o; tilep[NE] = tp;
    }
}

__global__ void k_scatter(const int* __restrict__ ids, const int* __restrict__ offsets,
                          int* __restrict__ cursors, int* __restrict__ bucket) {
    for (int i = blockIdx.x * blockDim.x + threadIdx.x; i < N_FEATS; i += gridDim.x * blockDim.x) {
        int e = ids[i];
        int p = atomicAdd(&cursors[e], 1);
        bucket[offsets[e] + p] = i;
    }
}

// ---------------- weight transpose + f32->bf16 ----------------
// src: [E][K][N] f32  ->  dst: [E][N][K] bf16   (K-contiguous for MFMA B-frags)
__global__ void k_transpose_cvt(const float* __restrict__ src, unsigned short* __restrict__ dst,
                                int K, int N) {
    __shared__ float tbuf[64][65];
    int e = blockIdx.z, k0 = blockIdx.x * 64, n0 = blockIdx.y * 64;
    int tx = threadIdx.x & 63, ty = threadIdx.x >> 6;   // 256 threads: 4 rows/pass
    const float* s = src + (size_t)e * K * N;
    unsigned short* d = dst + (size_t)e * N * K;
#pragma unroll
    for (int i = 0; i < 16; i++) {
        int k = i * 4 + ty;
        tbuf[k][tx] = s[(size_t)(k0 + k) * N + n0 + tx];
    }
    __syncthreads();
#pragma unroll
    for (int i = 0; i < 16; i++) {
        int n = i * 4 + ty;
        d[(size_t)(n0 + n) * K + k0 + tx] = f32_bf16(tbuf[tx][n]);
    }
}

// ---------------- fused grouped 2-layer MLP ----------------
// Per block: 64 rows of ONE expert, all 256 output cols. 4 waves, wave w owns
// out cols [64w, 64w+64). Hidden processed in 16 chunks of 64; relu'd h chunk
// round-trips through LDS (MFMA C-layout -> A-layout).
__global__ __launch_bounds__(256, 3) void k_mlp(
    const float* __restrict__ x, const float* __restrict__ b1, const float* __restrict__ b2,
    const unsigned short* __restrict__ w1t, const unsigned short* __restrict__ w2t,
    const int* __restrict__ bucket, const int* __restrict__ offsets,
    const int* __restrict__ tilep, float* __restrict__ out)
{
    __shared__ __align__(16) unsigned short xs[64][264];  // 64 rows x 256 k, +8 pad
    __shared__ __align__(16) unsigned short hs[64][72];   // 64 rows x 64 k, +8 pad
    __shared__ int rows_s[64];

    int b = blockIdx.x;
    if (b >= tilep[NE]) return;

    int e = 0;
#pragma unroll
    for (int i = 1; i < NE; i++) if (b >= tilep[i]) e = i;
    int tile = b - tilep[e];
    int off  = offsets[e];
    int cnt  = offsets[e + 1] - off;
    int valid = min(64, cnt - tile * 64);

    int t = threadIdx.x;
    int lane = t & 63, w = t >> 6;
    int l15 = lane & 15, quad = lane >> 4;

    if (t < 64)
        rows_s[t] = bucket[off + tile * 64 + min(t, valid - 1)];
    __syncthreads();

    // stage x tile: f32 -> bf16, row-major K-contiguous
    {
        int c = t & 63;      // float4 column 0..63
        int r4 = t >> 6;     // 0..3
#pragma unroll
        for (int p = 0; p < 16; p++) {
            int r = p * 4 + r4;
            float4 v = *((const float4*)(x + (size_t)rows_s[r] * IN_SZ) + c);
            ushort4 o;
            o.x = f32_bf16(v.x); o.y = f32_bf16(v.y);
            o.z = f32_bf16(v.z); o.w = f32_bf16(v.w);
            *(ushort4*)&xs[r][c * 4] = o;
        }
    }
    __syncthreads();

    floatx4 acc2[4][4] = {};  // [m-tile][n-tile], out cols w*64 + j*16 + l15
    const unsigned short* w1e = w1t + (size_t)e * HID * IN_SZ;
    const unsigned short* w2e = w2t + (size_t)e * OUT_SZ * HID;

    for (int hc = 0; hc < 16; hc++) {
        // ---- layer 1: this wave computes hidden cols n1 = hc*64 + w*16 + l15
        floatx4 acc1[4] = {};
        int n1 = hc * 64 + w * 16 + l15;
        const unsigned short* bbase = w1e + (size_t)n1 * IN_SZ + quad * 8;
#pragma unroll
        for (int ks = 0; ks < 8; ks++) {
            short8 bf = *(const short8*)(bbase + ks * 32);
#pragma unroll
            for (int i = 0; i < 4; i++) {
                short8 af = *(const short8*)&xs[16 * i + l15][ks * 32 + quad * 8];
                acc1[i] = __builtin_amdgcn_mfma_f32_16x16x32_bf16(af, bf, acc1[i], 0, 0, 0);
            }
        }
        // bias + relu, C-layout -> LDS row-major (A-layout for layer 2)
        float b1v = b1[e * HID + n1];
#pragma unroll
        for (int i = 0; i < 4; i++) {
#pragma unroll
            for (int r = 0; r < 4; r++) {
                float v = acc1[i][r] + b1v;
                v = v > 0.f ? v : 0.f;
                hs[16 * i + quad * 4 + r][w * 16 + l15] = f32_bf16(v);
            }
        }
        __syncthreads();
        // ---- layer 2: acc2 += h_chunk @ W2t[:, chunk]
#pragma unroll
        for (int ks = 0; ks < 2; ks++) {
            short8 af[4];
#pragma unroll
            for (int i = 0; i < 4; i++)
                af[i] = *(const short8*)&hs[16 * i + l15][ks * 32 + quad * 8];
#pragma unroll
            for (int j = 0; j < 4; j++) {
                int n2 = w * 64 + j * 16 + l15;
                short8 bf = *(const short8*)(w2e + (size_t)n2 * HID + hc * 64 + ks * 32 + quad * 8);
#pragma unroll
                for (int i = 0; i < 4; i++)
                    acc2[i][j] = __builtin_amdgcn_mfma_f32_16x16x32_bf16(af[i], bf, acc2[i][j], 0, 0, 0);
            }
        }
        __syncthreads();  // hs reads done before next chunk overwrites
    }

    // epilogue: + b2, scatter rows back
#pragma unroll
    for (int j = 0; j < 4; j++) {
        int col = w * 64 + j * 16 + l15;
        float b2v = b2[e * OUT_SZ + col];
#pragma unroll
        for (int i = 0; i < 4; i++) {
#pragma unroll
            for (int r = 0; r < 4; r++) {
                int rt = 16 * i + quad * 4 + r;
                if (rt < valid)
                    out[(size_t)rows_s[rt] * OUT_SZ + col] = acc2[i][j][r] + b2v;
            }
        }
    }
}

extern "C" void kernel_launch(void* const* d_in, const int* in_sizes, int n_in,
                              void* d_out, int out_size, void* d_ws, size_t ws_size,
                              hipStream_t stream) {
    const float* x  = (const float*)d_in[0];
    const float* W1 = (const float*)d_in[1];
    const float* b1 = (const float*)d_in[2];
    const float* W2 = (const float*)d_in[3];
    const float* b2 = (const float*)d_in[4];
    const int*  ids = (const int*)d_in[5];
    float* out = (float*)d_out;

    char* ws = (char*)d_ws;
    int* counts  = (int*)(ws);          // 16
    int* cursors = (int*)(ws + 64);     // 16
    int* offsets = (int*)(ws + 128);    // 17
    int* tilep   = (int*)(ws + 256);    // 17
    int* bucket  = (int*)(ws + 1024);   // 131072 ints
    unsigned short* w1t = (unsigned short*)(ws + (1 << 20));            // 8.39 MB
    unsigned short* w2t = w1t + (size_t)NE * HID * IN_SZ;               // 8.39 MB

    hipMemsetAsync(ws, 0, 512, stream);
    hipLaunchKernelGGL(k_hist,    dim3(256), dim3(256), 0, stream, ids, counts);
    hipLaunchKernelGGL(k_scan,    dim3(1),   dim3(1),   0, stream, counts, offsets, tilep);
    hipLaunchKernelGGL(k_scatter, dim3(512), dim3(256), 0, stream, ids, offsets, cursors, bucket);
    hipLaunchKernelGGL(k_transpose_cvt, dim3(IN_SZ / 64, HID / 64, NE), dim3(256), 0, stream,
                       W1, w1t, IN_SZ, HID);
    hipLaunchKernelGGL(k_transpose_cvt, dim3(HID / 64, OUT_SZ / 64, NE), dim3(256), 0, stream,
                       W2, w2t, HID, OUT_SZ);
    // max tiles = sum_e ceil(c_e/64) <= 131072/64 + 16 = 2064
    hipLaunchKernelGGL(k_mlp, dim3(2064), dim3(256), 0, stream,
                       x, b1, b2, w1t, w2t, bucket, offsets, tilep, out);
}

// Round 2
// 564.182 us; speedup vs baseline: 1.6250x; 1.6250x over previous
//
#include <hip/hip_runtime.h>
#include <stdint.h>

#define N_FEATS 131072
#define IN_SZ   256
#define HID     1024
#define OUT_SZ  256
#define NE      16

typedef __attribute__((ext_vector_type(8))) short short8;
typedef __attribute__((ext_vector_type(4))) float floatx4;

__device__ inline unsigned short f32_bf16(float f) {
    unsigned int u = __builtin_bit_cast(unsigned int, f);
    u += 0x7FFFu + ((u >> 16) & 1u);   // round-to-nearest-even
    return (unsigned short)(u >> 16);
}

// ---------------- bucketing ----------------
__global__ void k_hist(const int* __restrict__ ids, int* __restrict__ counts) {
    __shared__ int lc[NE];
    int t = threadIdx.x;
    if (t < NE) lc[t] = 0;
    __syncthreads();
    for (int i = blockIdx.x * blockDim.x + t; i < N_FEATS; i += gridDim.x * blockDim.x)
        atomicAdd(&lc[ids[i]], 1);
    __syncthreads();
    if (t < NE) atomicAdd(&counts[t], lc[t]);
}

__global__ void k_scan(const int* __restrict__ counts, int* __restrict__ offsets,
                       int* __restrict__ tilep) {
    if (threadIdx.x == 0 && blockIdx.x == 0) {
        int o = 0, tp = 0;
        for (int e = 0; e < NE; e++) {
            offsets[e] = o; tilep[e] = tp;
            o += counts[e];
            tp += (counts[e] + 63) >> 6;
        }
        offsets[NE] = o; tilep[NE] = tp;
    }
}

// Per-block aggregated scatter: LDS-local position assignment, ONE global
// atomicAdd per (expert,block) instead of one per element (16 vs 512).
// Round 1's per-element version serialized 8192 L2 atomics/address (~340us).
#define SC_CHUNK 512
__global__ void k_scatter(const int* __restrict__ ids, const int* __restrict__ offsets,
                          int* __restrict__ cursors, int* __restrict__ bucket) {
    __shared__ int lcnt[NE];
    __shared__ int lbase[NE];
    int t = threadIdx.x;
    int base = blockIdx.x * SC_CHUNK;
    if (t < NE) lcnt[t] = 0;
    __syncthreads();
    int i0 = base + t, i1 = base + 256 + t;
    int e0 = ids[i0], e1 = ids[i1];
    int p0 = atomicAdd(&lcnt[e0], 1);
    int p1 = atomicAdd(&lcnt[e1], 1);
    __syncthreads();
    if (t < NE) lbase[t] = atomicAdd(&cursors[t], lcnt[t]);
    __syncthreads();
    bucket[offsets[e0] + lbase[e0] + p0] = i0;
    bucket[offsets[e1] + lbase[e1] + p1] = i1;
}

// ---------------- weight transpose + f32->bf16 ----------------
// src: [E][K][N] f32  ->  dst: [E][N][K] bf16   (K-contiguous for MFMA B-frags)
__global__ void k_transpose_cvt(const float* __restrict__ src, unsigned short* __restrict__ dst,
                                int K, int N) {
    __shared__ float tbuf[64][65];
    int e = blockIdx.z, k0 = blockIdx.x * 64, n0 = blockIdx.y * 64;
    int tx = threadIdx.x & 63, ty = threadIdx.x >> 6;
    const float* s = src + (size_t)e * K * N;
    unsigned short* d = dst + (size_t)e * N * K;
#pragma unroll
    for (int i = 0; i < 16; i++) {
        int k = i * 4 + ty;
        tbuf[k][tx] = s[(size_t)(k0 + k) * N + n0 + tx];
    }
    __syncthreads();
#pragma unroll
    for (int i = 0; i < 16; i++) {
        int n = i * 4 + ty;
        d[(size_t)(n0 + n) * K + k0 + tx] = f32_bf16(tbuf[tx][n]);
    }
}

// ---------------- fused grouped 2-layer MLP ----------------
// 64 rows of one expert per block, 256 out cols, 4 waves (wave w: out cols
// [64w,64w+64)). Hidden in 8 chunks of 128 (16 barriers/block, was 32).
// xs/hs stored in MFMA A-fragment order [i][ks][lane][8] with XOR swizzle:
// b128 frag reads are contiguous-per-wave (conflict-free); swizzle spreads
// the staging writes across banks (round 1 layout was 8-way conflicted).
__global__ __launch_bounds__(256, 3) void k_mlp(
    const float* __restrict__ x, const float* __restrict__ b1, const float* __restrict__ b2,
    const unsigned short* __restrict__ w1t, const unsigned short* __restrict__ w2t,
    const int* __restrict__ bucket, const int* __restrict__ offsets,
    const int* __restrict__ tilep, float* __restrict__ out)
{
    // xs: A-frags of the 64x256 input tile: [i(4)][ks(8)][lane(64)][8] bf16 = 32 KB
    __shared__ __align__(16) unsigned short xs[4 * 8 * 64 * 8];
    // hs: A-frags of the 64x128 relu'd hidden chunk: [i(4)][ks2(4)][lane(64)][8] = 16 KB
    __shared__ __align__(16) unsigned short hs[4 * 4 * 64 * 8];
    __shared__ int rows_s[64];

    int b = blockIdx.x;
    if (b >= tilep[NE]) return;

    int e = 0;
#pragma unroll
    for (int i = 1; i < NE; i++) if (b >= tilep[i]) e = i;
    int tile = b - tilep[e];
    int off  = offsets[e];
    int cnt  = offsets[e + 1] - off;
    int valid = min(64, cnt - tile * 64);

    int t = threadIdx.x;
    int lane = t & 63, w = t >> 6;
    int l15 = lane & 15, quad = lane >> 4;

    if (t < 64)
        rows_s[t] = bucket[off + tile * 64 + min(t, valid - 1)];
    __syncthreads();

    // stage x tile f32->bf16 into A-frag order. item = p*256+t: c8 = item&31
    // (8-col group), r = item>>5. Global: 32 lanes x 32B = 1KB/row coalesced.
#pragma unroll
    for (int p = 0; p < 8; p++) {
        int item = p * 256 + t;
        int c8 = item & 31, r = item >> 5;
        const float* xr = x + (size_t)rows_s[r] * IN_SZ + c8 * 8;
        float4 v0 = *(const float4*)xr;
        float4 v1 = *(const float4*)(xr + 4);
        int ks = c8 >> 2, q = c8 & 3;
        short8 o;
        o[0] = (short)f32_bf16(v0.x); o[1] = (short)f32_bf16(v0.y);
        o[2] = (short)f32_bf16(v0.z); o[3] = (short)f32_bf16(v0.w);
        o[4] = (short)f32_bf16(v1.x); o[5] = (short)f32_bf16(v1.y);
        o[6] = (short)f32_bf16(v1.z); o[7] = (short)f32_bf16(v1.w);
        *(short8*)&xs[(((r >> 4) * 8 + ks) * 64 + q * 16 + ((r & 15) ^ ks)) * 8] = o;
    }
    __syncthreads();

    floatx4 acc2[4][4] = {};  // [m-tile][n-tile], out cols w*64 + j*16 + l15
    const unsigned short* w1e = w1t + (size_t)e * HID * IN_SZ;
    const unsigned short* w2e = w2t + (size_t)e * OUT_SZ * HID;

    for (int hc = 0; hc < 8; hc++) {
        // ---- layer 1: wave w computes hidden cols hc*128 + w*32 + j1*16 + l15
        floatx4 acc1[2][4] = {};
        int n1base = hc * 128 + w * 32;
        const unsigned short* bb0 = w1e + (size_t)(n1base + l15) * IN_SZ + quad * 8;
        const unsigned short* bb1 = w1e + (size_t)(n1base + 16 + l15) * IN_SZ + quad * 8;
#pragma unroll
        for (int ks = 0; ks < 8; ks++) {
            short8 bf0 = *(const short8*)(bb0 + ks * 32);
            short8 bf1 = *(const short8*)(bb1 + ks * 32);
            int xoff = (ks * 64 + quad * 16 + (l15 ^ ks)) * 8;
#pragma unroll
            for (int i = 0; i < 4; i++) {
                short8 af = *(const short8*)&xs[i * 4096 + xoff];
                acc1[0][i] = __builtin_amdgcn_mfma_f32_16x16x32_bf16(af, bf0, acc1[0][i], 0, 0, 0);
                acc1[1][i] = __builtin_amdgcn_mfma_f32_16x16x32_bf16(af, bf1, acc1[1][i], 0, 0, 0);
            }
        }
        // bias + relu; C-layout -> hs A-frag order (k chunk ks2 = w)
#pragma unroll
        for (int j1 = 0; j1 < 2; j1++) {
            float b1v = b1[e * HID + n1base + j1 * 16 + l15];
            int q2 = j1 * 2 + (l15 >> 3);
            int j2 = l15 & 7;
#pragma unroll
            for (int i = 0; i < 4; i++) {
#pragma unroll
                for (int r = 0; r < 4; r++) {
                    float v = acc1[j1][i][r] + b1v;
                    v = v > 0.f ? v : 0.f;
                    int m15 = quad * 4 + r;
                    hs[((i * 4 + w) * 64 + q2 * 16 + (m15 ^ q2)) * 8 + j2] = f32_bf16(v);
                }
            }
        }
        __syncthreads();
        // ---- layer 2: acc2 += h_chunk @ W2t[:, hc chunk]
#pragma unroll
        for (int ks2 = 0; ks2 < 4; ks2++) {
            int hoff = (ks2 * 64 + quad * 16 + (l15 ^ quad)) * 8;
            short8 af[4];
#pragma unroll
            for (int i = 0; i < 4; i++)
                af[i] = *(const short8*)&hs[i * 2048 + hoff];
#pragma unroll
            for (int j = 0; j < 4; j++) {
                int n2 = w * 64 + j * 16 + l15;
                short8 bf = *(const short8*)(w2e + (size_t)n2 * HID + hc * 128 + ks2 * 32 + quad * 8);
#pragma unroll
                for (int i = 0; i < 4; i++)
                    acc2[i][j] = __builtin_amdgcn_mfma_f32_16x16x32_bf16(af[i], bf, acc2[i][j], 0, 0, 0);
            }
        }
        __syncthreads();  // hs reads done before next chunk overwrites
    }

    // epilogue: + b2, scatter rows back
#pragma unroll
    for (int j = 0; j < 4; j++) {
        int col = w * 64 + j * 16 + l15;
        float b2v = b2[e * OUT_SZ + col];
#pragma unroll
        for (int i = 0; i < 4; i++) {
#pragma unroll
            for (int r = 0; r < 4; r++) {
                int rt = 16 * i + quad * 4 + r;
                if (rt < valid)
                    out[(size_t)rows_s[rt] * OUT_SZ + col] = acc2[i][j][r] + b2v;
            }
        }
    }
}

extern "C" void kernel_launch(void* const* d_in, const int* in_sizes, int n_in,
                              void* d_out, int out_size, void* d_ws, size_t ws_size,
                              hipStream_t stream) {
    const float* x  = (const float*)d_in[0];
    const float* W1 = (const float*)d_in[1];
    const float* b1 = (const float*)d_in[2];
    const float* W2 = (const float*)d_in[3];
    const float* b2 = (const float*)d_in[4];
    const int*  ids = (const int*)d_in[5];
    float* out = (float*)d_out;

    char* ws = (char*)d_ws;
    int* counts  = (int*)(ws);          // 16
    int* cursors = (int*)(ws + 64);     // 16
    int* offsets = (int*)(ws + 128);    // 17
    int* tilep   = (int*)(ws + 256);    // 17
    int* bucket  = (int*)(ws + 1024);   // 131072 ints
    unsigned short* w1t = (unsigned short*)(ws + (1 << 20));            // 8.39 MB
    unsigned short* w2t = w1t + (size_t)NE * HID * IN_SZ;               // 8.39 MB

    hipMemsetAsync(ws, 0, 512, stream);
    hipLaunchKernelGGL(k_hist,    dim3(256), dim3(256), 0, stream, ids, counts);
    hipLaunchKernelGGL(k_scan,    dim3(1),   dim3(1),   0, stream, counts, offsets, tilep);
    hipLaunchKernelGGL(k_scatter, dim3(N_FEATS / SC_CHUNK), dim3(256), 0, stream,
                       ids, offsets, cursors, bucket);
    hipLaunchKernelGGL(k_transpose_cvt, dim3(IN_SZ / 64, HID / 64, NE), dim3(256), 0, stream,
                       W1, w1t, IN_SZ, HID);
    hipLaunchKernelGGL(k_transpose_cvt, dim3(HID / 64, OUT_SZ / 64, NE), dim3(256), 0, stream,
                       W2, w2t, HID, OUT_SZ);
    // max tiles = sum_e ceil(c_e/64) <= 131072/64 + 16 = 2064
    hipLaunchKernelGGL(k_mlp, dim3(2064), dim3(256), 0, stream,
                       x, b1, b2, w1t, w2t, bucket, offsets, tilep, out);
}

// Round 3
// 535.143 us; speedup vs baseline: 1.7131x; 1.0543x over previous
//
#include <hip/hip_runtime.h>
#include <stdint.h>

#define N_FEATS 131072
#define IN_SZ   256
#define HID     1024
#define OUT_SZ  256
#define NE      16

typedef __attribute__((ext_vector_type(8))) short short8;
typedef __attribute__((ext_vector_type(4))) float floatx4;

__device__ inline unsigned short f32_bf16(float f) {
    unsigned int u = __builtin_bit_cast(unsigned int, f);
    u += 0x7FFFu + ((u >> 16) & 1u);   // round-to-nearest-even
    return (unsigned short)(u >> 16);
}

// ---------------- bucketing ----------------
__global__ void k_hist(const int* __restrict__ ids, int* __restrict__ counts) {
    __shared__ int lc[NE];
    int t = threadIdx.x;
    if (t < NE) lc[t] = 0;
    __syncthreads();
    for (int i = blockIdx.x * blockDim.x + t; i < N_FEATS; i += gridDim.x * blockDim.x)
        atomicAdd(&lc[ids[i]], 1);
    __syncthreads();
    if (t < NE) atomicAdd(&counts[t], lc[t]);
}

__global__ void k_scan(const int* __restrict__ counts, int* __restrict__ offsets,
                       int* __restrict__ tilep) {
    if (threadIdx.x == 0 && blockIdx.x == 0) {
        int o = 0, tp = 0;
        for (int e = 0; e < NE; e++) {
            offsets[e] = o; tilep[e] = tp;
            o += counts[e];
            tp += (counts[e] + 63) >> 6;
        }
        offsets[NE] = o; tilep[NE] = tp;
    }
}

// Per-block aggregated scatter (round 1's per-element global atomics were ~340us).
#define SC_CHUNK 512
__global__ void k_scatter(const int* __restrict__ ids, const int* __restrict__ offsets,
                          int* __restrict__ cursors, int* __restrict__ bucket) {
    __shared__ int lcnt[NE];
    __shared__ int lbase[NE];
    int t = threadIdx.x;
    int base = blockIdx.x * SC_CHUNK;
    if (t < NE) lcnt[t] = 0;
    __syncthreads();
    int i0 = base + t, i1 = base + 256 + t;
    int e0 = ids[i0], e1 = ids[i1];
    int p0 = atomicAdd(&lcnt[e0], 1);
    int p1 = atomicAdd(&lcnt[e1], 1);
    __syncthreads();
    if (t < NE) lbase[t] = atomicAdd(&cursors[t], lcnt[t]);
    __syncthreads();
    bucket[offsets[e0] + lbase[e0] + p0] = i0;
    bucket[offsets[e1] + lbase[e1] + p1] = i1;
}

// ---------------- weight pack: f32 [E][K][N] -> bf16 MFMA-B-frag order ----------------
// dst layout: [E][N/16][K/32][lane(64)][8], lane = quad*16 + l15 holds
// B[k = ks*32 + quad*8 + j][n = n16*16 + l15]. A wave's fragment load becomes
// base + lane*8: one contiguous aligned 1 KB burst (round 2's row-major layout
// made every weight load touch 16 lines 512B apart -> TA divergence).
// grid: (K/256, N/16, E), block 256.
__global__ void k_pack(const float* __restrict__ src, unsigned short* __restrict__ dst,
                       int K, int N) {
    __shared__ float ld[256][17];
    int kc = blockIdx.x, n16 = blockIdx.y, e = blockIdx.z;
    int t = threadIdx.x;
    const float* s = src + ((size_t)e * K + kc * 256) * N + n16 * 16;
    int tn = t & 15, tk = t >> 4;
#pragma unroll
    for (int p = 0; p < 16; p++) {
        int k = p * 16 + tk;
        ld[k][tn] = s[(size_t)k * N + tn];
    }
    __syncthreads();
    unsigned short* d = dst + (((size_t)e * (N / 16) + n16) * (K / 32) + kc * 8) * 512;
#pragma unroll
    for (int u = 0; u < 2; u++) {
        int o = t * 16 + u * 8;           // short8 element offset
        int ks = o >> 9;                  // local ks 0..7
        int lane = (o >> 3) & 63;
        int kbase = ks * 32 + ((lane >> 4) & 3) * 8;
        int n = lane & 15;
        short8 v;
#pragma unroll
        for (int j = 0; j < 8; j++) v[j] = (short)f32_bf16(ld[kbase + j][n]);
        *(short8*)(d + o) = v;
    }
}

// ---------------- fused grouped 2-layer MLP ----------------
// Identical structure to round 2 (64 rows/block, 4 waves, hidden chunk 128,
// xs/hs in swizzled A-frag order). Only change: weight loads now hit the
// packed frag-order layout -> contiguous per-wave 1 KB loads.
__global__ __launch_bounds__(256, 3) void k_mlp(
    const float* __restrict__ x, const float* __restrict__ b1, const float* __restrict__ b2,
    const unsigned short* __restrict__ w1fr, const unsigned short* __restrict__ w2fr,
    const int* __restrict__ bucket, const int* __restrict__ offsets,
    const int* __restrict__ tilep, float* __restrict__ out)
{
    __shared__ __align__(16) unsigned short xs[4 * 8 * 64 * 8];  // 32 KB
    __shared__ __align__(16) unsigned short hs[4 * 4 * 64 * 8];  // 16 KB
    __shared__ int rows_s[64];

    int b = blockIdx.x;
    if (b >= tilep[NE]) return;

    int e = 0;
#pragma unroll
    for (int i = 1; i < NE; i++) if (b >= tilep[i]) e = i;
    int tile = b - tilep[e];
    int off  = offsets[e];
    int cnt  = offsets[e + 1] - off;
    int valid = min(64, cnt - tile * 64);

    int t = threadIdx.x;
    int lane = t & 63, w = t >> 6;
    int l15 = lane & 15, quad = lane >> 4;

    if (t < 64)
        rows_s[t] = bucket[off + tile * 64 + min(t, valid - 1)];
    __syncthreads();

    // stage x tile f32->bf16 into swizzled A-frag order
#pragma unroll
    for (int p = 0; p < 8; p++) {
        int item = p * 256 + t;
        int c8 = item & 31, r = item >> 5;
        const float* xr = x + (size_t)rows_s[r] * IN_SZ + c8 * 8;
        float4 v0 = *(const float4*)xr;
        float4 v1 = *(const float4*)(xr + 4);
        int ks = c8 >> 2, q = c8 & 3;
        short8 o;
        o[0] = (short)f32_bf16(v0.x); o[1] = (short)f32_bf16(v0.y);
        o[2] = (short)f32_bf16(v0.z); o[3] = (short)f32_bf16(v0.w);
        o[4] = (short)f32_bf16(v1.x); o[5] = (short)f32_bf16(v1.y);
        o[6] = (short)f32_bf16(v1.z); o[7] = (short)f32_bf16(v1.w);
        *(short8*)&xs[(((r >> 4) * 8 + ks) * 64 + q * 16 + ((r & 15) ^ ks)) * 8] = o;
    }
    __syncthreads();

    floatx4 acc2[4][4] = {};  // [m-tile][n-tile], out cols w*64 + j*16 + l15
    const unsigned short* w1e = w1fr + (size_t)e * 64 * 4096;        // 64 n16 x (8 ks x 512)
    const unsigned short* w2e = w2fr + (size_t)e * 16 * 32 * 512;    // 16 n16 x (32 kst x 512)

    for (int hc = 0; hc < 8; hc++) {
        // ---- layer 1: wave w computes hidden cols hc*128 + w*32 + j1*16 + l15
        floatx4 acc1[2][4] = {};
        int n16_0 = hc * 8 + w * 2;
        const unsigned short* bb0 = w1e + (size_t)n16_0 * 4096 + lane * 8;
        const unsigned short* bb1 = bb0 + 4096;
#pragma unroll
        for (int ks = 0; ks < 8; ks++) {
            short8 bf0 = *(const short8*)(bb0 + ks * 512);
            short8 bf1 = *(const short8*)(bb1 + ks * 512);
            int xoff = (ks * 64 + quad * 16 + (l15 ^ ks)) * 8;
#pragma unroll
            for (int i = 0; i < 4; i++) {
                short8 af = *(const short8*)&xs[i * 4096 + xoff];
                acc1[0][i] = __builtin_amdgcn_mfma_f32_16x16x32_bf16(af, bf0, acc1[0][i], 0, 0, 0);
                acc1[1][i] = __builtin_amdgcn_mfma_f32_16x16x32_bf16(af, bf1, acc1[1][i], 0, 0, 0);
            }
        }
        // bias + relu; C-layout -> hs A-frag order
        int n1base = hc * 128 + w * 32;
#pragma unroll
        for (int j1 = 0; j1 < 2; j1++) {
            float b1v = b1[e * HID + n1base + j1 * 16 + l15];
            int q2 = j1 * 2 + (l15 >> 3);
            int j2 = l15 & 7;
#pragma unroll
            for (int i = 0; i < 4; i++) {
#pragma unroll
                for (int r = 0; r < 4; r++) {
                    float v = acc1[j1][i][r] + b1v;
                    v = v > 0.f ? v : 0.f;
                    int m15 = quad * 4 + r;
                    hs[((i * 4 + w) * 64 + q2 * 16 + (m15 ^ q2)) * 8 + j2] = f32_bf16(v);
                }
            }
        }
        __syncthreads();
        // ---- layer 2: acc2 += h_chunk @ W2 chunk
#pragma unroll
        for (int ks2 = 0; ks2 < 4; ks2++) {
            int hoff = (ks2 * 64 + quad * 16 + (l15 ^ quad)) * 8;
            short8 af[4];
#pragma unroll
            for (int i = 0; i < 4; i++)
                af[i] = *(const short8*)&hs[i * 2048 + hoff];
#pragma unroll
            for (int j = 0; j < 4; j++) {
                short8 bf = *(const short8*)(w2e + (((size_t)(w * 4 + j) * 32) + hc * 4 + ks2) * 512 + lane * 8);
#pragma unroll
                for (int i = 0; i < 4; i++)
                    acc2[i][j] = __builtin_amdgcn_mfma_f32_16x16x32_bf16(af[i], bf, acc2[i][j], 0, 0, 0);
            }
        }
        __syncthreads();
    }

    // epilogue: + b2, scatter rows back
#pragma unroll
    for (int j = 0; j < 4; j++) {
        int col = w * 64 + j * 16 + l15;
        float b2v = b2[e * OUT_SZ + col];
#pragma unroll
        for (int i = 0; i < 4; i++) {
#pragma unroll
            for (int r = 0; r < 4; r++) {
                int rt = 16 * i + quad * 4 + r;
                if (rt < valid)
                    out[(size_t)rows_s[rt] * OUT_SZ + col] = acc2[i][j][r] + b2v;
            }
        }
    }
}

extern "C" void kernel_launch(void* const* d_in, const int* in_sizes, int n_in,
                              void* d_out, int out_size, void* d_ws, size_t ws_size,
                              hipStream_t stream) {
    const float* x  = (const float*)d_in[0];
    const float* W1 = (const float*)d_in[1];
    const float* b1 = (const float*)d_in[2];
    const float* W2 = (const float*)d_in[3];
    const float* b2 = (const float*)d_in[4];
    const int*  ids = (const int*)d_in[5];
    float* out = (float*)d_out;

    char* ws = (char*)d_ws;
    int* counts  = (int*)(ws);          // 16
    int* cursors = (int*)(ws + 64);     // 16
    int* offsets = (int*)(ws + 128);    // 17
    int* tilep   = (int*)(ws + 256);    // 17
    int* bucket  = (int*)(ws + 1024);   // 131072 ints
    unsigned short* w1fr = (unsigned short*)(ws + (1 << 20));           // 8.39 MB
    unsigned short* w2fr = w1fr + (size_t)NE * HID * IN_SZ;             // 8.39 MB

    hipMemsetAsync(ws, 0, 512, stream);
    hipLaunchKernelGGL(k_hist,    dim3(256), dim3(256), 0, stream, ids, counts);
    hipLaunchKernelGGL(k_scan,    dim3(1),   dim3(1),   0, stream, counts, offsets, tilep);
    hipLaunchKernelGGL(k_scatter, dim3(N_FEATS / SC_CHUNK), dim3(256), 0, stream,
                       ids, offsets, cursors, bucket);
    // W1: [16][256][1024] -> frag order; W2: [16][1024][256] -> frag order
    hipLaunchKernelGGL(k_pack, dim3(IN_SZ / 256, HID / 16, NE), dim3(256), 0, stream,
                       W1, w1fr, IN_SZ, HID);
    hipLaunchKernelGGL(k_pack, dim3(HID / 256, OUT_SZ / 16, NE), dim3(256), 0, stream,
                       W2, w2fr, HID, OUT_SZ);
    hipLaunchKernelGGL(k_mlp, dim3(2064), dim3(256), 0, stream,
                       x, b1, b2, w1fr, w2fr, bucket, offsets, tilep, out);
}